// Round 1
// baseline (1930.462 us; speedup 1.0000x reference)
//
#include <hip/hip_runtime.h>
#include <hip/hip_bf16.h>

#define N_NODES 50000
#define N_EDGES 800000

// ---------------- degree accumulation ----------------
__global__ __launch_bounds__(256) void deg_kernel(const int* __restrict__ src,
                                                  const int* __restrict__ dst,
                                                  float* __restrict__ deg_out,
                                                  float* __restrict__ deg_in) {
    int e = blockIdx.x * 256 + threadIdx.x;
    if (e < N_EDGES) {
        atomicAdd(&deg_out[src[e]], 1.0f);
        atomicAdd(&deg_in[dst[e]], 1.0f);
    }
}

// deg -> clipped rsqrt norm, in place
__global__ __launch_bounds__(256) void norm_kernel(float* __restrict__ deg_out,
                                                   float* __restrict__ deg_in) {
    int i = blockIdx.x * 256 + threadIdx.x;
    if (i < N_NODES) {
        deg_out[i] = 1.0f / sqrtf(fmaxf(deg_out[i], 1.0f));
        deg_in[i]  = 1.0f / sqrtf(fmaxf(deg_in[i], 1.0f));
    }
}

// ---------------- GEMM1: hp[i][j] = dn_out[i] * sum_k feat[i][k]*W1[k][j] ----------------
// 8 rows/block, 256 threads: thread = (col j in [0,128), row-half rh in {0,1} -> 4 rows each)
__global__ __launch_bounds__(256) void gemm1_kernel(const float* __restrict__ feat,
                                                    const float* __restrict__ W1,
                                                    const float* __restrict__ dn_out,
                                                    float* __restrict__ hp) {
    __shared__ float fs[256 * 8];   // [k][r] layout so 4 rows read as one float4
    int base = blockIdx.x * 8;
    int tid = threadIdx.x;
    for (int idx = tid; idx < 2048; idx += 256) {
        int r = idx >> 8, k = idx & 255;
        int row = base + r;
        float v = 0.0f;
        if (row < N_NODES) v = feat[row * 256 + k] * dn_out[row];
        fs[k * 8 + r] = v;
    }
    __syncthreads();
    int j = tid & 127;
    int rh = tid >> 7;   // 0 or 1
    float acc0 = 0.f, acc1 = 0.f, acc2 = 0.f, acc3 = 0.f;
    const float4* fs4 = (const float4*)fs;
#pragma unroll 8
    for (int k = 0; k < 256; ++k) {
        float w = W1[k * 128 + j];
        float4 f = fs4[k * 2 + rh];   // broadcast across the wave
        acc0 += f.x * w; acc1 += f.y * w; acc2 += f.z * w; acc3 += f.w * w;
    }
    int r0 = base + rh * 4;
    if (r0 + 0 < N_NODES) hp[(r0 + 0) * 128 + j] = acc0;
    if (r0 + 1 < N_NODES) hp[(r0 + 1) * 128 + j] = acc1;
    if (r0 + 2 < N_NODES) hp[(r0 + 2) * 128 + j] = acc2;
    if (r0 + 3 < N_NODES) hp[(r0 + 3) * 128 + j] = acc3;
}

// ---------------- edge aggregation, 128-wide: 32 threads per edge, float4 each ----------------
__global__ __launch_bounds__(256) void agg1_kernel(const int* __restrict__ src,
                                                   const int* __restrict__ dst,
                                                   const float* __restrict__ hp,
                                                   float* __restrict__ hagg) {
    int t = blockIdx.x * 256 + threadIdx.x;
    int e = t >> 5;
    if (e >= N_EDGES) return;
    int j4 = (t & 31) * 4;
    int s = src[e], d = dst[e];
    const float4 v = *(const float4*)&hp[s * 128 + j4];
    float* o = &hagg[d * 128 + j4];
    atomicAdd(o + 0, v.x);
    atomicAdd(o + 1, v.y);
    atomicAdd(o + 2, v.z);
    atomicAdd(o + 3, v.w);
}

// ---------------- GEMM2 with fused relu(m*dn_in+b1) input, dn_out output scale ----------------
// 8 rows/block, 256 threads: thread = (col j in [0,32), row r in [0,8))
__global__ __launch_bounds__(256) void gemm2_kernel(const float* __restrict__ hagg,
                                                    const float* __restrict__ W2,
                                                    const float* __restrict__ b1,
                                                    const float* __restrict__ dn_in,
                                                    const float* __restrict__ dn_out,
                                                    float* __restrict__ hp2) {
    __shared__ float hs[8][128];
    int base = blockIdx.x * 8;
    int tid = threadIdx.x;
    for (int idx = tid; idx < 1024; idx += 256) {
        int r = idx >> 7, k = idx & 127;
        int row = base + r;
        float v = 0.0f;
        if (row < N_NODES) {
            v = hagg[row * 128 + k] * dn_in[row] + b1[k];
            v = fmaxf(v, 0.0f);            // relu (layer-1 activation)
        }
        hs[r][k] = v;
    }
    __syncthreads();
    int j = tid & 31;
    int r = tid >> 5;
    float acc = 0.0f;
#pragma unroll 8
    for (int k = 0; k < 128; ++k) {
        acc += hs[r][k] * W2[k * 32 + j];
    }
    int row = base + r;
    if (row < N_NODES) hp2[row * 32 + j] = acc * dn_out[row];
}

// ---------------- edge aggregation, 32-wide: 8 threads per edge, float4 each ----------------
__global__ __launch_bounds__(256) void agg2_kernel(const int* __restrict__ src,
                                                   const int* __restrict__ dst,
                                                   const float* __restrict__ hp2,
                                                   float* __restrict__ hagg2) {
    int t = blockIdx.x * 256 + threadIdx.x;
    int e = t >> 3;
    if (e >= N_EDGES) return;
    int j4 = (t & 7) * 4;
    int s = src[e], d = dst[e];
    const float4 v = *(const float4*)&hp2[s * 32 + j4];
    float* o = &hagg2[d * 32 + j4];
    atomicAdd(o + 0, v.x);
    atomicAdd(o + 1, v.y);
    atomicAdd(o + 2, v.z);
    atomicAdd(o + 3, v.w);
}

// ---------------- fused bias + log_softmax over 32 classes ----------------
__global__ __launch_bounds__(256) void lsm_kernel(const float* __restrict__ hagg2,
                                                  const float* __restrict__ b2,
                                                  const float* __restrict__ dn_in,
                                                  float* __restrict__ out) {
    int tid = threadIdx.x;
    int j = tid & 31;
    int r = blockIdx.x * 8 + (tid >> 5);
    if (r >= N_NODES) return;
    float x = hagg2[r * 32 + j] * dn_in[r] + b2[j];
    float mx = x;
    for (int m = 16; m; m >>= 1) mx = fmaxf(mx, __shfl_xor(mx, m, 32));
    float ex = expf(x - mx);
    float s = ex;
    for (int m = 16; m; m >>= 1) s += __shfl_xor(s, m, 32);
    out[r * 32 + j] = x - mx - logf(s);
}

extern "C" void kernel_launch(void* const* d_in, const int* in_sizes, int n_in,
                              void* d_out, int out_size, void* d_ws, size_t ws_size,
                              hipStream_t stream) {
    const float* feat = (const float*)d_in[0];
    const int*   src  = (const int*)d_in[1];
    const int*   dst  = (const int*)d_in[2];
    const float* W1   = (const float*)d_in[3];
    const float* b1   = (const float*)d_in[4];
    const float* W2   = (const float*)d_in[5];
    const float* b2   = (const float*)d_in[6];
    float* out = (float*)d_out;

    float* ws = (float*)d_ws;
    // layout (floats): [deg_out | deg_in | h1_agg | h2_agg | h1_proj | h2_proj]
    float* deg_out = ws;                              // 50000
    float* deg_in  = ws + 50000;                      // 50000
    float* h1_agg  = ws + 100000;                     // 50000*128 = 6.4M
    float* h2_agg  = ws + 100000 + 6400000;           // 50000*32  = 1.6M
    float* h1_proj = ws + 100000 + 8000000;           // 6.4M
    float* h2_proj = ws + 100000 + 14400000;          // 1.6M

    // zero the accumulated regions (deg_out, deg_in, h1_agg, h2_agg are contiguous)
    size_t zero_bytes = (size_t)(100000 + 6400000 + 1600000) * sizeof(float);
    hipMemsetAsync(d_ws, 0, zero_bytes, stream);

    deg_kernel<<<(N_EDGES + 255) / 256, 256, 0, stream>>>(src, dst, deg_out, deg_in);
    norm_kernel<<<(N_NODES + 255) / 256, 256, 0, stream>>>(deg_out, deg_in);
    gemm1_kernel<<<(N_NODES + 7) / 8, 256, 0, stream>>>(feat, W1, deg_out, h1_proj);
    agg1_kernel<<<(N_EDGES * 32 + 255) / 256, 256, 0, stream>>>(src, dst, h1_proj, h1_agg);
    gemm2_kernel<<<(N_NODES + 7) / 8, 256, 0, stream>>>(h1_agg, W2, b1, deg_in, deg_out, h2_proj);
    agg2_kernel<<<(N_EDGES * 8 + 255) / 256, 256, 0, stream>>>(src, dst, h2_proj, h2_agg);
    lsm_kernel<<<(N_NODES + 7) / 8, 256, 0, stream>>>(h2_agg, b2, deg_in, out);
}

// Round 3
// 409.934 us; speedup vs baseline: 4.7092x; 4.7092x over previous
//
#include <hip/hip_runtime.h>
#include <hip/hip_bf16.h>

#define N_NODES 50000
#define N_EDGES 800000
#define NB_SCAN 196   // ceil(50000/256)

// ---------------- degree histograms (int atomics) ----------------
__global__ __launch_bounds__(256) void hist_kernel(const int* __restrict__ src,
                                                   const int* __restrict__ dst,
                                                   int* __restrict__ cnt_src,
                                                   int* __restrict__ cnt_dst) {
    int e = blockIdx.x * 256 + threadIdx.x;
    if (e < N_EDGES) {
        atomicAdd(&cnt_src[src[e]], 1);
        atomicAdd(&cnt_dst[dst[e]], 1);
    }
}

// int degrees -> clipped rsqrt norms
__global__ __launch_bounds__(256) void norm_kernel(const int* __restrict__ cnt_src,
                                                   const int* __restrict__ cnt_dst,
                                                   float* __restrict__ dn_out,
                                                   float* __restrict__ dn_in) {
    int i = blockIdx.x * 256 + threadIdx.x;
    if (i < N_NODES) {
        dn_out[i] = 1.0f / sqrtf(fmaxf((float)cnt_src[i], 1.0f));
        dn_in[i]  = 1.0f / sqrtf(fmaxf((float)cnt_dst[i], 1.0f));
    }
}

// ---------------- 3-kernel exclusive scan of cnt_dst -> row_start ----------------
__global__ __launch_bounds__(256) void scan1_kernel(const int* __restrict__ cnt,
                                                    int* __restrict__ row_start,
                                                    int* __restrict__ blocksum) {
    __shared__ int s[256];
    int i = blockIdx.x * 256 + threadIdx.x;
    int v = (i < N_NODES) ? cnt[i] : 0;
    s[threadIdx.x] = v;
    __syncthreads();
    for (int off = 1; off < 256; off <<= 1) {
        int t = (threadIdx.x >= off) ? s[threadIdx.x - off] : 0;
        __syncthreads();
        s[threadIdx.x] += t;
        __syncthreads();
    }
    if (i < N_NODES) row_start[i] = s[threadIdx.x] - v;   // exclusive
    if (threadIdx.x == 255) blocksum[blockIdx.x] = s[255];
}

__global__ __launch_bounds__(256) void scan2_kernel(int* __restrict__ blocksum) {
    __shared__ int s[256];
    int v = (threadIdx.x < NB_SCAN) ? blocksum[threadIdx.x] : 0;
    s[threadIdx.x] = v;
    __syncthreads();
    for (int off = 1; off < 256; off <<= 1) {
        int t = (threadIdx.x >= off) ? s[threadIdx.x - off] : 0;
        __syncthreads();
        s[threadIdx.x] += t;
        __syncthreads();
    }
    if (threadIdx.x < NB_SCAN) blocksum[threadIdx.x] = s[threadIdx.x] - v;  // exclusive
}

__global__ __launch_bounds__(256) void scan3_kernel(int* __restrict__ row_start,
                                                    const int* __restrict__ blocksum) {
    int i = blockIdx.x * 256 + threadIdx.x;
    if (i < N_NODES) row_start[i] += blocksum[blockIdx.x];
}

// ---------------- CSR bucket fill (edge list sorted by dst) ----------------
__global__ __launch_bounds__(256) void fill_kernel(const int* __restrict__ src,
                                                   const int* __restrict__ dst,
                                                   const int* __restrict__ row_start,
                                                   int* __restrict__ cursor,
                                                   int* __restrict__ edge_src) {
    int e = blockIdx.x * 256 + threadIdx.x;
    if (e < N_EDGES) {
        int d = dst[e];
        int p = atomicAdd(&cursor[d], 1);
        edge_src[row_start[d] + p] = src[e];
    }
}

// ---------------- GEMM1: hp[i][j] = dn_out[i] * sum_k feat[i][k]*W1[k][j] ----------------
__global__ __launch_bounds__(256) void gemm1_kernel(const float* __restrict__ feat,
                                                    const float* __restrict__ W1,
                                                    const float* __restrict__ dn_out,
                                                    float* __restrict__ hp) {
    __shared__ float fs[256 * 8];   // [k][r] so 4 rows read as one float4
    int base = blockIdx.x * 8;
    int tid = threadIdx.x;
    for (int idx = tid; idx < 2048; idx += 256) {
        int r = idx >> 8, k = idx & 255;
        int row = base + r;
        float v = 0.0f;
        if (row < N_NODES) v = feat[row * 256 + k] * dn_out[row];
        fs[k * 8 + r] = v;
    }
    __syncthreads();
    int j = tid & 127;
    int rh = tid >> 7;
    float acc0 = 0.f, acc1 = 0.f, acc2 = 0.f, acc3 = 0.f;
    const float4* fs4 = (const float4*)fs;
#pragma unroll 8
    for (int k = 0; k < 256; ++k) {
        float w = W1[k * 128 + j];
        float4 f = fs4[k * 2 + rh];
        acc0 += f.x * w; acc1 += f.y * w; acc2 += f.z * w; acc3 += f.w * w;
    }
    int r0 = base + rh * 4;
    if (r0 + 0 < N_NODES) hp[(r0 + 0) * 128 + j] = acc0;
    if (r0 + 1 < N_NODES) hp[(r0 + 1) * 128 + j] = acc1;
    if (r0 + 2 < N_NODES) hp[(r0 + 2) * 128 + j] = acc2;
    if (r0 + 3 < N_NODES) hp[(r0 + 3) * 128 + j] = acc3;
}

// ---------------- layer-1 gather-aggregate + fused epilogue ----------------
// wave per node, 64 lanes x float2 columns.
// h1s[n][c] = relu(acc[c]*dn_in[n] + b1[c]) * dn_out[n]   (dn_out = layer-2 source norm)
__global__ __launch_bounds__(256) void agg1_kernel(const int* __restrict__ row_start,
                                                   const int* __restrict__ cnt_dst,
                                                   const int* __restrict__ edge_src,
                                                   const float* __restrict__ hp,
                                                   const float* __restrict__ dn_in,
                                                   const float* __restrict__ dn_out,
                                                   const float* __restrict__ b1,
                                                   float* __restrict__ h1s) {
    int wid = threadIdx.x >> 6;
    int lane = threadIdx.x & 63;
    int n = blockIdx.x * 4 + wid;
    if (n >= N_NODES) return;
    int beg = row_start[n];
    int len = cnt_dst[n];
    int c = lane * 2;
    float ax = 0.f, ay = 0.f;
    int j = 0;
    for (; j + 1 < len; j += 2) {
        int s0 = edge_src[beg + j];
        int s1 = edge_src[beg + j + 1];
        float2 v0 = *(const float2*)&hp[s0 * 128 + c];
        float2 v1 = *(const float2*)&hp[s1 * 128 + c];
        ax += v0.x + v1.x;
        ay += v0.y + v1.y;
    }
    if (j < len) {
        int s0 = edge_src[beg + j];
        float2 v0 = *(const float2*)&hp[s0 * 128 + c];
        ax += v0.x;
        ay += v0.y;
    }
    float dn_i = dn_in[n], dn_o = dn_out[n];
    float x0 = fmaxf(ax * dn_i + b1[c], 0.f) * dn_o;
    float x1 = fmaxf(ay * dn_i + b1[c + 1], 0.f) * dn_o;
    float2 r = make_float2(x0, x1);
    *(float2*)&h1s[n * 128 + c] = r;
}

// ---------------- GEMM2 (pure): hp2 = h1s @ W2 ----------------
__global__ __launch_bounds__(256) void gemm2_kernel(const float* __restrict__ h1s,
                                                    const float* __restrict__ W2,
                                                    float* __restrict__ hp2) {
    __shared__ float hs[8][128];
    int base = blockIdx.x * 8;
    int tid = threadIdx.x;
    for (int idx = tid; idx < 1024; idx += 256) {
        int r = idx >> 7, k = idx & 127;
        int row = base + r;
        hs[r][k] = (row < N_NODES) ? h1s[row * 128 + k] : 0.0f;
    }
    __syncthreads();
    int j = tid & 31;
    int r = tid >> 5;
    float acc = 0.0f;
#pragma unroll 8
    for (int k = 0; k < 128; ++k) {
        acc += hs[r][k] * W2[k * 32 + j];
    }
    int row = base + r;
    if (row < N_NODES) hp2[row * 32 + j] = acc;
}

// ---------------- layer-2 gather-aggregate + bias + log_softmax ----------------
// 32 lanes per node, 8 nodes per block.
__global__ __launch_bounds__(256) void agg2lsm_kernel(const int* __restrict__ row_start,
                                                      const int* __restrict__ cnt_dst,
                                                      const int* __restrict__ edge_src,
                                                      const float* __restrict__ hp2,
                                                      const float* __restrict__ dn_in,
                                                      const float* __restrict__ b2,
                                                      float* __restrict__ out) {
    int g = threadIdx.x >> 5;
    int lane = threadIdx.x & 31;
    int n = blockIdx.x * 8 + g;
    if (n >= N_NODES) return;
    int beg = row_start[n];
    int len = cnt_dst[n];
    float acc = 0.f;
    int j = 0;
    for (; j + 1 < len; j += 2) {
        int s0 = edge_src[beg + j];
        int s1 = edge_src[beg + j + 1];
        acc += hp2[s0 * 32 + lane] + hp2[s1 * 32 + lane];
    }
    if (j < len) acc += hp2[edge_src[beg + j] * 32 + lane];
    float x = acc * dn_in[n] + b2[lane];
    float mx = x;
    for (int m = 16; m; m >>= 1) mx = fmaxf(mx, __shfl_xor(mx, m, 32));
    float ex = expf(x - mx);
    float s = ex;
    for (int m = 16; m; m >>= 1) s += __shfl_xor(s, m, 32);
    out[n * 32 + lane] = x - mx - logf(s);
}

extern "C" void kernel_launch(void* const* d_in, const int* in_sizes, int n_in,
                              void* d_out, int out_size, void* d_ws, size_t ws_size,
                              hipStream_t stream) {
    const float* feat = (const float*)d_in[0];
    const int*   src  = (const int*)d_in[1];
    const int*   dst  = (const int*)d_in[2];
    const float* W1   = (const float*)d_in[3];
    const float* b1   = (const float*)d_in[4];
    const float* W2   = (const float*)d_in[5];
    const float* b2   = (const float*)d_in[6];
    float* out = (float*)d_out;

    // workspace layout, 4-byte units
    int*   iws      = (int*)d_ws;
    int*   cnt_src  = iws;                 // 50000   (reused as cursor for fill)
    int*   cnt_dst  = iws + 50000;         // 50000
    int*   row_start= iws + 100000;        // 50000
    int*   blocksum = iws + 150000;        // 256
    int*   edge_src = iws + 150256;        // 800000
    float* fws      = (float*)d_ws;
    float* dn_out   = fws + 950256;        // 50000
    float* dn_in    = fws + 1000256;       // 50000
    float* h1_proj  = fws + 1050256;       // 6.4M
    float* h1s      = fws + 7450256;       // 6.4M
    float* hp2      = fws + 13850256;      // 1.6M
    // total 15,450,256 * 4B = 61.8 MB

    // zero histograms (cnt_src, cnt_dst contiguous)
    hipMemsetAsync(cnt_src, 0, 100000 * sizeof(int), stream);

    const int EB = (N_EDGES + 255) / 256;
    const int NBn = (N_NODES + 255) / 256;

    hist_kernel<<<EB, 256, 0, stream>>>(src, dst, cnt_src, cnt_dst);
    norm_kernel<<<NBn, 256, 0, stream>>>(cnt_src, cnt_dst, dn_out, dn_in);
    scan1_kernel<<<NB_SCAN, 256, 0, stream>>>(cnt_dst, row_start, blocksum);
    scan2_kernel<<<1, 256, 0, stream>>>(blocksum);
    scan3_kernel<<<NB_SCAN, 256, 0, stream>>>(row_start, blocksum);
    // cnt_src no longer needed (norms done) -> reuse as cursor
    hipMemsetAsync(cnt_src, 0, 50000 * sizeof(int), stream);
    fill_kernel<<<EB, 256, 0, stream>>>(src, dst, row_start, cnt_src, edge_src);

    gemm1_kernel<<<(N_NODES + 7) / 8, 256, 0, stream>>>(feat, W1, dn_out, h1_proj);
    agg1_kernel<<<(N_NODES + 3) / 4, 256, 0, stream>>>(row_start, cnt_dst, edge_src,
                                                       h1_proj, dn_in, dn_out, b1, h1s);
    gemm2_kernel<<<(N_NODES + 7) / 8, 256, 0, stream>>>(h1s, W2, hp2);
    agg2lsm_kernel<<<(N_NODES + 7) / 8, 256, 0, stream>>>(row_start, cnt_dst, edge_src,
                                                          hp2, dn_in, b2, out);
}

// Round 4
// 331.916 us; speedup vs baseline: 5.8161x; 1.2351x over previous
//
#include <hip/hip_runtime.h>
#include <hip/hip_bf16.h>

#define N_NODES 50000
#define N_EDGES 800000
#define NB_SCAN 196   // ceil(50000/256)

typedef __bf16 bf16_t;
typedef bf16_t bf16x8 __attribute__((ext_vector_type(8)));
typedef float  f32x4  __attribute__((ext_vector_type(4)));

static __device__ __forceinline__ float bfhi_to_f(uint v) {   // high 16 bits as bf16
    return __builtin_bit_cast(float, v & 0xffff0000u);
}
static __device__ __forceinline__ float bflo_to_f(uint v) {   // low 16 bits as bf16
    return __builtin_bit_cast(float, v << 16);
}
static __device__ __forceinline__ ushort f_to_bf(float x) {   // RNE via hw cvt
    bf16_t q = (bf16_t)x;
    return __builtin_bit_cast(ushort, q);
}

// ---------------- degree histograms (int atomics) ----------------
__global__ __launch_bounds__(256) void hist_kernel(const int* __restrict__ src,
                                                   const int* __restrict__ dst,
                                                   int* __restrict__ cnt_src,
                                                   int* __restrict__ cnt_dst) {
    int e = blockIdx.x * 256 + threadIdx.x;
    if (e < N_EDGES) {
        atomicAdd(&cnt_src[src[e]], 1);
        atomicAdd(&cnt_dst[dst[e]], 1);
    }
}

// int degrees -> clipped rsqrt norms
__global__ __launch_bounds__(256) void norm_kernel(const int* __restrict__ cnt_src,
                                                   const int* __restrict__ cnt_dst,
                                                   float* __restrict__ dn_out,
                                                   float* __restrict__ dn_in) {
    int i = blockIdx.x * 256 + threadIdx.x;
    if (i < N_NODES) {
        dn_out[i] = 1.0f / sqrtf(fmaxf((float)cnt_src[i], 1.0f));
        dn_in[i]  = 1.0f / sqrtf(fmaxf((float)cnt_dst[i], 1.0f));
    }
}

// ---------------- W1T/W2T bf16 transposed weight prep ----------------
// W1T[j][k] = bf16(W1[k][j])  (128 x 256);  W2T[j][k] = bf16(W2[k][j])  (32 x 128)
__global__ __launch_bounds__(256) void prep_w_kernel(const float* __restrict__ W1,
                                                     const float* __restrict__ W2,
                                                     ushort* __restrict__ W1T,
                                                     ushort* __restrict__ W2T) {
    int i = blockIdx.x * 256 + threadIdx.x;
    if (i < 32768) {
        int j = i >> 8, k = i & 255;
        W1T[i] = f_to_bf(W1[k * 128 + j]);
    }
    if (i < 4096) {
        int j = i >> 7, k = i & 127;
        W2T[i] = f_to_bf(W2[k * 32 + j]);
    }
}

// ---------------- 3-kernel exclusive scan of cnt_dst -> row_start ----------------
__global__ __launch_bounds__(256) void scan1_kernel(const int* __restrict__ cnt,
                                                    int* __restrict__ row_start,
                                                    int* __restrict__ blocksum) {
    __shared__ int s[256];
    int i = blockIdx.x * 256 + threadIdx.x;
    int v = (i < N_NODES) ? cnt[i] : 0;
    s[threadIdx.x] = v;
    __syncthreads();
    for (int off = 1; off < 256; off <<= 1) {
        int t = (threadIdx.x >= off) ? s[threadIdx.x - off] : 0;
        __syncthreads();
        s[threadIdx.x] += t;
        __syncthreads();
    }
    if (i < N_NODES) row_start[i] = s[threadIdx.x] - v;   // exclusive
    if (threadIdx.x == 255) blocksum[blockIdx.x] = s[255];
}

__global__ __launch_bounds__(256) void scan2_kernel(int* __restrict__ blocksum) {
    __shared__ int s[256];
    int v = (threadIdx.x < NB_SCAN) ? blocksum[threadIdx.x] : 0;
    s[threadIdx.x] = v;
    __syncthreads();
    for (int off = 1; off < 256; off <<= 1) {
        int t = (threadIdx.x >= off) ? s[threadIdx.x - off] : 0;
        __syncthreads();
        s[threadIdx.x] += t;
        __syncthreads();
    }
    if (threadIdx.x < NB_SCAN) blocksum[threadIdx.x] = s[threadIdx.x] - v;  // exclusive
}

__global__ __launch_bounds__(256) void scan3_kernel(int* __restrict__ row_start,
                                                    const int* __restrict__ blocksum) {
    int i = blockIdx.x * 256 + threadIdx.x;
    if (i < N_NODES) row_start[i] += blocksum[blockIdx.x];
}

// ---------------- CSR bucket fill (edge list sorted by dst) ----------------
__global__ __launch_bounds__(256) void fill_kernel(const int* __restrict__ src,
                                                   const int* __restrict__ dst,
                                                   const int* __restrict__ row_start,
                                                   int* __restrict__ cursor,
                                                   int* __restrict__ edge_src) {
    int e = blockIdx.x * 256 + threadIdx.x;
    if (e < N_EDGES) {
        int d = dst[e];
        int p = atomicAdd(&cursor[d], 1);
        edge_src[row_start[d] + p] = src[e];
    }
}

// ---------------- GEMM1 (MFMA): hp = bf16( (feat*dn_out) @ W1 ) ----------------
// one wave per 16-row strip; 50000 = 16*3125 exactly.
__global__ __launch_bounds__(256) void gemm1_kernel(const float* __restrict__ feat,
                                                    const ushort* __restrict__ W1T,
                                                    const float* __restrict__ dn_out,
                                                    ushort* __restrict__ hp) {
    int wave = (blockIdx.x * 256 + threadIdx.x) >> 6;
    if (wave >= 3125) return;
    int lane = threadIdx.x & 63;
    int r0 = wave * 16;
    int row = r0 + (lane & 15);          // A-fragment row (lane%16)
    int ksel = (lane >> 4) * 8;          // A/B fragment k base (8 contiguous)
    float scale = dn_out[row];
    const float* fr = feat + row * 256 + ksel;
    const bf16x8* w1 = (const bf16x8*)W1T;   // element (j*256+k)/8 = j*32 + k/8

    f32x4 acc[8];
#pragma unroll
    for (int jt = 0; jt < 8; ++jt) acc[jt] = (f32x4){0.f, 0.f, 0.f, 0.f};

#pragma unroll
    for (int kc = 0; kc < 8; ++kc) {     // K = 256 in chunks of 32
        float4 f0 = *(const float4*)(fr + kc * 32);
        float4 f1 = *(const float4*)(fr + kc * 32 + 4);
        bf16x8 a;
        a[0] = (bf16_t)(f0.x * scale); a[1] = (bf16_t)(f0.y * scale);
        a[2] = (bf16_t)(f0.z * scale); a[3] = (bf16_t)(f0.w * scale);
        a[4] = (bf16_t)(f1.x * scale); a[5] = (bf16_t)(f1.y * scale);
        a[6] = (bf16_t)(f1.z * scale); a[7] = (bf16_t)(f1.w * scale);
        int kidx = (kc * 32 + ksel) >> 3;
#pragma unroll
        for (int jt = 0; jt < 8; ++jt) {
            int j = jt * 16 + (lane & 15);
            bf16x8 b = w1[j * 32 + kidx];
            acc[jt] = __builtin_amdgcn_mfma_f32_16x16x32_bf16(a, b, acc[jt], 0, 0, 0);
        }
    }
    // D: col = lane&15 (within tile), row = (lane>>4)*4 + reg   [m89-verified]
    int rbase = r0 + (lane >> 4) * 4;
#pragma unroll
    for (int jt = 0; jt < 8; ++jt) {
        int j = jt * 16 + (lane & 15);
#pragma unroll
        for (int r = 0; r < 4; ++r) {
            hp[(rbase + r) * 128 + j] = f_to_bf(acc[jt][r]);
        }
    }
}

// ---------------- layer-1 gather-aggregate + fused epilogue (bf16 in/out) ----------------
// wave per node; lane owns cols {2l, 2l+1} -> one uint (2x bf16) per edge.
__global__ __launch_bounds__(256) void agg1_kernel(const int* __restrict__ row_start,
                                                   const int* __restrict__ cnt_dst,
                                                   const int* __restrict__ edge_src,
                                                   const ushort* __restrict__ hp,
                                                   const float* __restrict__ dn_in,
                                                   const float* __restrict__ dn_out,
                                                   const float* __restrict__ b1,
                                                   ushort* __restrict__ h1s) {
    int wid = threadIdx.x >> 6;
    int lane = threadIdx.x & 63;
    int n = blockIdx.x * 4 + wid;
    if (n >= N_NODES) return;
    int beg = row_start[n];
    int len = cnt_dst[n];
    int c = lane * 2;
    float ax = 0.f, ay = 0.f;
    int j = 0;
    for (; j + 1 < len; j += 2) {
        int s0 = edge_src[beg + j];
        int s1 = edge_src[beg + j + 1];
        uint v0 = *(const uint*)(hp + s0 * 128 + c);
        uint v1 = *(const uint*)(hp + s1 * 128 + c);
        ax += bflo_to_f(v0) + bflo_to_f(v1);
        ay += bfhi_to_f(v0) + bfhi_to_f(v1);
    }
    if (j < len) {
        uint v0 = *(const uint*)(hp + edge_src[beg + j] * 128 + c);
        ax += bflo_to_f(v0);
        ay += bfhi_to_f(v0);
    }
    float dn_i = dn_in[n], dn_o = dn_out[n];
    float x0 = fmaxf(ax * dn_i + b1[c], 0.f) * dn_o;
    float x1 = fmaxf(ay * dn_i + b1[c + 1], 0.f) * dn_o;
    uint pk = (uint)f_to_bf(x0) | ((uint)f_to_bf(x1) << 16);
    *(uint*)(h1s + n * 128 + c) = pk;
}

// ---------------- GEMM2 (MFMA): hp2 = bf16( h1s @ W2 ) ----------------
__global__ __launch_bounds__(256) void gemm2_kernel(const ushort* __restrict__ h1s,
                                                    const ushort* __restrict__ W2T,
                                                    ushort* __restrict__ hp2) {
    int wave = (blockIdx.x * 256 + threadIdx.x) >> 6;
    if (wave >= 3125) return;
    int lane = threadIdx.x & 63;
    int r0 = wave * 16;
    int row = r0 + (lane & 15);
    int ksel = (lane >> 4) * 8;
    const bf16x8* av = (const bf16x8*)(h1s + row * 128);
    const bf16x8* w2 = (const bf16x8*)W2T;   // element (j*128+k)/8 = j*16 + k/8

    f32x4 acc[2];
    acc[0] = (f32x4){0.f, 0.f, 0.f, 0.f};
    acc[1] = (f32x4){0.f, 0.f, 0.f, 0.f};
#pragma unroll
    for (int kc = 0; kc < 4; ++kc) {     // K = 128 in chunks of 32
        bf16x8 a = av[kc * 4 + (lane >> 4)];
#pragma unroll
        for (int jt = 0; jt < 2; ++jt) {
            int j = jt * 16 + (lane & 15);
            bf16x8 b = w2[j * 16 + kc * 4 + (lane >> 4)];
            acc[jt] = __builtin_amdgcn_mfma_f32_16x16x32_bf16(a, b, acc[jt], 0, 0, 0);
        }
    }
    int rbase = r0 + (lane >> 4) * 4;
#pragma unroll
    for (int jt = 0; jt < 2; ++jt) {
        int j = jt * 16 + (lane & 15);
#pragma unroll
        for (int r = 0; r < 4; ++r) {
            hp2[(rbase + r) * 32 + j] = f_to_bf(acc[jt][r]);
        }
    }
}

// ---------------- layer-2 gather-aggregate + bias + log_softmax ----------------
// 32 lanes per node, 8 nodes per block; hp2 is bf16 (2 B/lane/edge).
__global__ __launch_bounds__(256) void agg2lsm_kernel(const int* __restrict__ row_start,
                                                      const int* __restrict__ cnt_dst,
                                                      const int* __restrict__ edge_src,
                                                      const ushort* __restrict__ hp2,
                                                      const float* __restrict__ dn_in,
                                                      const float* __restrict__ b2,
                                                      float* __restrict__ out) {
    int g = threadIdx.x >> 5;
    int lane = threadIdx.x & 31;
    int n = blockIdx.x * 8 + g;
    if (n >= N_NODES) return;
    int beg = row_start[n];
    int len = cnt_dst[n];
    float acc = 0.f;
    int j = 0;
    for (; j + 1 < len; j += 2) {
        int s0 = edge_src[beg + j];
        int s1 = edge_src[beg + j + 1];
        float v0 = bflo_to_f((uint)hp2[s0 * 32 + lane]);
        float v1 = bflo_to_f((uint)hp2[s1 * 32 + lane]);
        acc += v0 + v1;
    }
    if (j < len) acc += bflo_to_f((uint)hp2[edge_src[beg + j] * 32 + lane]);
    float x = acc * dn_in[n] + b2[lane];
    float mx = x;
    for (int m = 16; m; m >>= 1) mx = fmaxf(mx, __shfl_xor(mx, m, 32));
    float ex = expf(x - mx);
    float s = ex;
    for (int m = 16; m; m >>= 1) s += __shfl_xor(s, m, 32);
    out[n * 32 + lane] = x - mx - logf(s);
}

extern "C" void kernel_launch(void* const* d_in, const int* in_sizes, int n_in,
                              void* d_out, int out_size, void* d_ws, size_t ws_size,
                              hipStream_t stream) {
    const float* feat = (const float*)d_in[0];
    const int*   src  = (const int*)d_in[1];
    const int*   dst  = (const int*)d_in[2];
    const float* W1   = (const float*)d_in[3];
    const float* b1   = (const float*)d_in[4];
    const float* W2   = (const float*)d_in[5];
    const float* b2   = (const float*)d_in[6];
    float* out = (float*)d_out;

    // workspace layout, 4-byte units
    int*   iws      = (int*)d_ws;
    int*   cnt_src  = iws;                 // 50000   (reused as cursor for fill)
    int*   cnt_dst  = iws + 50000;         // 50000
    int*   row_start= iws + 100000;        // 50000
    int*   blocksum = iws + 150000;        // 256
    int*   edge_src = iws + 150256;        // 800000 -> ends 950256
    float* fws      = (float*)d_ws;
    float* dn_out   = fws + 950256;        // 50000
    float* dn_in    = fws + 1000256;       // 50000 -> ends 1050256
    ushort* W1T = (ushort*)(fws + 1050256);  // 32768 bf16 -> 16384 units, ends 1066640
    ushort* W2T = (ushort*)(fws + 1066640);  // 4096 bf16  -> 2048 units,  ends 1068688
    ushort* hp  = (ushort*)(fws + 1068688);  // 6.4M bf16  -> 3.2M units,  ends 4268688
    ushort* h1s = (ushort*)(fws + 4268688);  // 6.4M bf16  -> 3.2M units,  ends 7468688
    ushort* hp2 = (ushort*)(fws + 7468688);  // 1.6M bf16  -> 0.8M units,  ends 8268688 (~33 MB)

    // zero histograms (cnt_src, cnt_dst contiguous)
    hipMemsetAsync(cnt_src, 0, 100000 * sizeof(int), stream);

    const int EB = (N_EDGES + 255) / 256;
    const int NBn = (N_NODES + 255) / 256;

    hist_kernel<<<EB, 256, 0, stream>>>(src, dst, cnt_src, cnt_dst);
    norm_kernel<<<NBn, 256, 0, stream>>>(cnt_src, cnt_dst, dn_out, dn_in);
    prep_w_kernel<<<128, 256, 0, stream>>>(W1, W2, W1T, W2T);
    scan1_kernel<<<NB_SCAN, 256, 0, stream>>>(cnt_dst, row_start, blocksum);
    scan2_kernel<<<1, 256, 0, stream>>>(blocksum);
    scan3_kernel<<<NB_SCAN, 256, 0, stream>>>(row_start, blocksum);
    // cnt_src no longer needed (norms done) -> reuse as cursor
    hipMemsetAsync(cnt_src, 0, 50000 * sizeof(int), stream);
    fill_kernel<<<EB, 256, 0, stream>>>(src, dst, row_start, cnt_src, edge_src);

    gemm1_kernel<<<(3125 * 64 + 255) / 256, 256, 0, stream>>>(feat, W1T, dn_out, hp);
    agg1_kernel<<<(N_NODES + 3) / 4, 256, 0, stream>>>(row_start, cnt_dst, edge_src,
                                                       hp, dn_in, dn_out, b1, h1s);
    gemm2_kernel<<<(3125 * 64 + 255) / 256, 256, 0, stream>>>(h1s, W2T, hp2);
    agg2lsm_kernel<<<(N_NODES + 7) / 8, 256, 0, stream>>>(row_start, cnt_dst, edge_src,
                                                          hp2, dn_in, b2, out);
}